// Round 9
// baseline (232.034 us; speedup 1.0000x reference)
//
#include <hip/hip_runtime.h>
#include <math.h>

typedef __bf16 bf16;
typedef bf16 bf16x4 __attribute__((ext_vector_type(4)));
typedef bf16 bf16x8 __attribute__((ext_vector_type(8)));
typedef float f32x4 __attribute__((ext_vector_type(4)));

static_assert(sizeof(bf16x8) == 16, "bf16x8 must be 16B");

// q pre-scale: (1/sqrt(hd=32)) * log2(e)  -> softmax via exp2
#define QSCALE (0.17677669529663687f * 1.4426950408889634f)

__device__ __forceinline__ f32x4 mfma16(bf16x8 a, bf16x8 b, f32x4 c) {
  return __builtin_amdgcn_mfma_f32_16x16x32_bf16(a, b, c, 0, 0, 0);
}

// ---------------------------------------------------------------------------
// 1) FUSED weight prep + sr conv.
//    blocks [0, nsr): dwconv7x7 s4 p3 + BN1 + GELU + scale + BN2 -> kv1 bf16
//    blocks [nsr, nsr+96): Wq->bf16 (32 blks), Wkv->bf16 (64 blks)
//    sr is branch-free: all loads issued before any use (r5 lesson: a
//    12-VGPR body serializes 13 HBM latencies).
// ---------------------------------------------------------------------------
__global__ __launch_bounds__(256) void k_pre(
    const float* __restrict__ x, const float* __restrict__ w7,
    const float* __restrict__ g1, const float* __restrict__ b1,
    const float* __restrict__ m1, const float* __restrict__ v1,
    const float* __restrict__ sw2,
    const float* __restrict__ g2, const float* __restrict__ b2,
    const float* __restrict__ m2, const float* __restrict__ v2,
    const float* __restrict__ Wq, const float* __restrict__ Wkv,
    bf16* __restrict__ Wqb, bf16* __restrict__ Wkvb,
    bf16* __restrict__ kv1, int nsr) {
  __shared__ float part[4][256];
  const int tid = threadIdx.x;
  const int blk = blockIdx.x;

  if (blk >= nsr) {                              // ---- weight conversion ----
    const int wb = blk - nsr;
    const float* src;
    bf16* dst;
    if (wb < 32) {
      const int idx = wb * 256 + tid;            // Wq: 65536/8 = 8192
      src = Wq + (size_t)idx * 8;
      dst = Wqb + (size_t)idx * 8;
    } else {
      const int idx = (wb - 32) * 256 + tid;     // Wkv: 131072/8 = 16384
      src = Wkv + (size_t)idx * 8;
      dst = Wkvb + (size_t)idx * 8;
    }
    const float4 a = ((const float4*)src)[0];
    const float4 b = ((const float4*)src)[1];
    bf16x8 r;
    r[0] = (bf16)a.x; r[1] = (bf16)a.y; r[2] = (bf16)a.z; r[3] = (bf16)a.w;
    r[4] = (bf16)b.x; r[5] = (bf16)b.y; r[6] = (bf16)b.z; r[7] = (bf16)b.w;
    *(bf16x8*)dst = r;
    return;
  }
  // ---- sr conv: 64 ch-groups x 4 tap-teams (team == wave) ----
  const int team = tid >> 6, g = tid & 63;
  const int c0 = g * 4;
  const int b = blk & 7, m = blk >> 3;
  const int oy = m >> 4, ox = m & 15;

  float4 xv[13];
  float wj[13][4], msk[13];
  #pragma unroll
  for (int j = 0; j < 13; j++) {               // issue ALL loads first
    const int tap = team + j * 4;
    const int ky = tap / 7, kx = tap - ky * 7;
    const int iy = oy * 4 - 3 + ky, ix = ox * 4 - 3 + kx;
    msk[j] = (tap < 49 && iy >= 0 && iy < 64 && ix >= 0 && ix < 64) ? 1.f : 0.f;
    const int iyc = iy < 0 ? 0 : (iy > 63 ? 63 : iy);
    const int ixc = ix < 0 ? 0 : (ix > 63 ? 63 : ix);
    const int tc = tap > 48 ? 48 : tap;
    xv[j] = *(const float4*)(x + ((size_t)b * 4096 + iyc * 64 + ixc) * 256 + c0);
    #pragma unroll
    for (int i = 0; i < 4; i++) wj[j][i] = w7[(c0 + i) * 49 + tc];
  }
  float a0 = 0.f, a1 = 0.f, a2 = 0.f, a3 = 0.f;
  #pragma unroll
  for (int j = 0; j < 13; j++) {
    a0 += xv[j].x * wj[j][0] * msk[j];
    a1 += xv[j].y * wj[j][1] * msk[j];
    a2 += xv[j].z * wj[j][2] * msk[j];
    a3 += xv[j].w * wj[j][3] * msk[j];
  }
  *(f32x4*)&part[team][c0] = (f32x4){a0, a1, a2, a3};
  __syncthreads();
  const int c = tid;
  float y = part[0][c] + part[1][c] + part[2][c] + part[3][c];
  float s = g1[c] / sqrtf(v1[c] + 1e-5f);
  y = y * s + (b1[c] - m1[c] * s);
  y = 0.5f * y * (1.f + erff(y * 0.70710678118654752f));   // exact GELU
  y *= sw2[c];
  s = g2[c] / sqrtf(v2[c] + 1e-5f);
  y = y * s + (b2[c] - m2[c] * s);
  kv1[((size_t)b * 256 + m) * 256 + c] = (bf16)y;
}

// ---------------------------------------------------------------------------
// 2) FUSED local dw3x3(+bias+residual) + KV projection.
//    grid (32, B): block = 8 pixels. Halo in LDS -> conv -> fp32 rows -> GEMV.
//    dd<256 -> K (bh, m, hd) bf16; dd>=256 -> V^T (bh, hd, m)
// ---------------------------------------------------------------------------
__global__ __launch_bounds__(256) void k_localkv(
    const bf16* __restrict__ kv1, const float* __restrict__ w3,
    const float* __restrict__ lb, const bf16* __restrict__ Wkvb,
    const float* __restrict__ bkv, bf16* __restrict__ k_a,
    bf16* __restrict__ v_b) {
  __shared__ bf16 halo[3][10][256];
  __shared__ float rows[8][256];
  const int c = threadIdx.x;
  const int mt = blockIdx.x;   // 32 tiles of 8 pixels
  const int b = blockIdx.y;
  const int oy = mt >> 1, o0 = (mt & 1) * 8;

  #pragma unroll
  for (int p = 0; p < 30; p++) {
    const int dy = p / 10, xi = p - dy * 10;
    const int iy = oy - 1 + dy, ix = o0 - 1 + xi;
    const bool ok = (iy >= 0 && iy < 16 && ix >= 0 && ix < 16);
    const int iyc = ok ? iy : 0, ixc = ok ? ix : 0;
    const bf16 v = kv1[((size_t)b * 256 + iyc * 16 + ixc) * 256 + c];
    halo[dy][xi][c] = ok ? v : (bf16)0.f;
  }
  float w3f[9];
  #pragma unroll
  for (int t = 0; t < 9; t++) w3f[t] = w3[c * 9 + t];
  const float lbf = lb[c];
  __syncthreads();

  #pragma unroll
  for (int r = 0; r < 8; r++) {
    float acc = lbf + (float)halo[1][r + 1][c];   // bias + residual center
    #pragma unroll
    for (int ky = 0; ky < 3; ky++)
      #pragma unroll
      for (int kx = 0; kx < 3; kx++)
        acc += (float)halo[ky][r + kx][c] * w3f[ky * 3 + kx];
    rows[r][c] = acc;
  }
  __syncthreads();

  const int tid = c;
  float acck[8] = {0}, accv[8] = {0};
  for (int oc = 0; oc < 32; oc++) {
    const bf16x8 w0 = *(const bf16x8*)(Wkvb + (size_t)tid * 256 + oc * 8);
    const bf16x8 w1 = *(const bf16x8*)(Wkvb + ((size_t)tid + 256) * 256 + oc * 8);
    float wf0[8], wf1[8];
    #pragma unroll
    for (int j = 0; j < 8; j++) { wf0[j] = (float)w0[j]; wf1[j] = (float)w1[j]; }
    #pragma unroll
    for (int r = 0; r < 8; r++) {
      const float4* rp = (const float4*)&rows[r][oc * 8];
      const float4 ra = rp[0], rb = rp[1];
      const float rv[8] = {ra.x, ra.y, ra.z, ra.w, rb.x, rb.y, rb.z, rb.w};
      #pragma unroll
      for (int j = 0; j < 8; j++) {
        acck[r] += wf0[j] * rv[j];
        accv[r] += wf1[j] * rv[j];
      }
    }
  }
  const float bk = bkv[tid], bv = bkv[tid + 256];
  const int h = tid >> 5, d = tid & 31;
  #pragma unroll
  for (int r = 0; r < 8; r++) {
    const int m = (oy * 16 + o0) + r;
    k_a[(((size_t)b * 8 + h) * 256 + m) * 32 + d] = (bf16)(acck[r] + bk);
    v_b[(((size_t)b * 8 + h) * 32 + d) * 256 + m] = (bf16)(accv[r] + bv);
  }
}

// ---------------------------------------------------------------------------
// 3) FUSED Q projection + attention. grid (16, 8, B) = (ntile, h, b).
//    Phase 1: q[256 queries x 32 d] = x . Wq[h-slice]^T via MFMA, x staged
//      per-kc in LDS (row stride 40 elems: 16B-aligned, <=2-way banks).
//      D (C-layout) -> bias+QSCALE -> bf16 -> LDS round-trip into B-operand
//      layout (reuses the dead x-staging rows; wave-private, no barrier).
//    Phase 2: no-max softmax attention (r8): S^T = K.Q^T, p=exp2, O^T=V^T.P^T.
//    K rows permuted at load so P lands directly in B-operand layout.
// ---------------------------------------------------------------------------
__global__ __launch_bounds__(256) void k_qattn(
    const float* __restrict__ x, const bf16* __restrict__ Wqb,
    const float* __restrict__ bq, const bf16* __restrict__ k_a,
    const bf16* __restrict__ v_b, float* __restrict__ out) {
  __shared__ bf16 xs[256 * 40];                // 20.5 KB, stride 40 elems
  const int tid = threadIdx.x;
  const int wv = tid >> 6, lane = tid & 63;
  const int qd = lane >> 4, l15 = lane & 15;
  const int nt = blockIdx.x, h = blockIdx.y, b = blockIdx.z;
  const int bh = b * 8 + h;
  const size_t brow0 = (size_t)b * 4096 + nt * 256;   // block's first x row

  // ---- phase 1: q-tiles. D[qi][dt]: d = dt*16+qd*4+r, query = qi*16+l15 ----
  f32x4 dq0[4], dq1[4];
  #pragma unroll
  for (int qi = 0; qi < 4; qi++) {
    dq0[qi] = (f32x4){0.f, 0.f, 0.f, 0.f};
    dq1[qi] = (f32x4){0.f, 0.f, 0.f, 0.f};
  }
  for (int kc = 0; kc < 8; kc++) {
    __syncthreads();                           // xs safe to overwrite
    #pragma unroll
    for (int j = 0; j < 8; j++) {              // stage 256 rows x 32 ch
      const int e = j * 1024 + tid * 4;        // coalesced 16B per lane
      const int r = e >> 5, c = e & 31;
      const float4 v = *(const float4*)(x + (brow0 + r) * 256 + kc * 32 + c);
      bf16x4 bv;
      bv[0] = (bf16)v.x; bv[1] = (bf16)v.y; bv[2] = (bf16)v.z; bv[3] = (bf16)v.w;
      *(bf16x4*)(xs + r * 40 + c) = bv;
    }
    __syncthreads();
    // A-frags: Wq rows (m = d_local = dt*16+l15, k = c = kc*32+qd*8+j)
    const bf16x8 a0 = *(const bf16x8*)(Wqb + (size_t)(h * 32 + l15) * 256 + kc * 32 + qd * 8);
    const bf16x8 a1 = *(const bf16x8*)(Wqb + (size_t)(h * 32 + 16 + l15) * 256 + kc * 32 + qd * 8);
    #pragma unroll
    for (int qi = 0; qi < 4; qi++) {
      // B-frag: x^T (k = c, n = query): lane reads its own wave's row
      const bf16x8 bb = *(const bf16x8*)(xs + (wv * 64 + qi * 16 + l15) * 40 + qd * 8);
      dq0[qi] = mfma16(a0, bb, dq0[qi]);
      dq1[qi] = mfma16(a1, bb, dq1[qi]);
    }
  }
  // bias + QSCALE, C-layout -> B-layout via wave-private LDS (reuse own rows)
  const float4 bq0 = *(const float4*)(bq + h * 32 + qd * 4);
  const float4 bq1 = *(const float4*)(bq + h * 32 + 16 + qd * 4);
  bf16* ql = xs + (size_t)wv * 64 * 40;
  #pragma unroll
  for (int qi = 0; qi < 4; qi++) {
    bf16x4 q0, q1;
    q0[0] = (bf16)((dq0[qi][0] + bq0.x) * QSCALE);
    q0[1] = (bf16)((dq0[qi][1] + bq0.y) * QSCALE);
    q0[2] = (bf16)((dq0[qi][2] + bq0.z) * QSCALE);
    q0[3] = (bf16)((dq0[qi][3] + bq0.w) * QSCALE);
    q1[0] = (bf16)((dq1[qi][0] + bq1.x) * QSCALE);
    q1[1] = (bf16)((dq1[qi][1] + bq1.y) * QSCALE);
    q1[2] = (bf16)((dq1[qi][2] + bq1.z) * QSCALE);
    q1[3] = (bf16)((dq1[qi][3] + bq1.w) * QSCALE);
    *(bf16x4*)(ql + (qi * 16 + l15) * 40 + qd * 4) = q0;
    *(bf16x4*)(ql + (qi * 16 + l15) * 40 + 16 + qd * 4) = q1;
  }
  bf16x8 qf[4];   // B-operand: lane holds Q^T[d=qd*8+j][query=l15]
  #pragma unroll
  for (int qi = 0; qi < 4; qi++)
    qf[qi] = *(const bf16x8*)(ql + (qi * 16 + l15) * 40 + qd * 8);

  // ---- phase 2: attention (no-max softmax; overflow-guard clamp only) ----
  const bf16* kb = k_a + (size_t)bh * 256 * 32;
  const bf16* vb = v_b + (size_t)bh * 32 * 256;

  f32x4 acc[4][2];
  float lr[4] = {0.f, 0.f, 0.f, 0.f};
  #pragma unroll
  for (int qi = 0; qi < 4; qi++) {
    acc[qi][0] = (f32x4){0.f, 0.f, 0.f, 0.f};
    acc[qi][1] = (f32x4){0.f, 0.f, 0.f, 0.f};
  }
  // permuted key row: A-tile t row l15 holds key 8*(l15>>2) + 4*t + (l15&3)
  const int kperm = 8 * (l15 >> 2) + (l15 & 3);

  bf16x8 ka0 = *(const bf16x8*)(kb + (size_t)kperm * 32 + qd * 8);
  bf16x8 ka1 = *(const bf16x8*)(kb + (size_t)(kperm + 4) * 32 + qd * 8);
  bf16x8 va0 = *(const bf16x8*)(vb + (size_t)l15 * 256 + qd * 8);
  bf16x8 va1 = *(const bf16x8*)(vb + (size_t)(16 + l15) * 256 + qd * 8);

  for (int ch = 0; ch < 8; ch++) {               // 8 chunks x 32 keys
    const int cn = (ch < 7 ? ch + 1 : 7) * 32;   // prefetch next (clamped)
    const bf16x8 nk0 = *(const bf16x8*)(kb + (size_t)(cn + kperm) * 32 + qd * 8);
    const bf16x8 nk1 = *(const bf16x8*)(kb + (size_t)(cn + kperm + 4) * 32 + qd * 8);
    const bf16x8 nv0 = *(const bf16x8*)(vb + (size_t)l15 * 256 + cn + qd * 8);
    const bf16x8 nv1 = *(const bf16x8*)(vb + (size_t)(16 + l15) * 256 + cn + qd * 8);
    const f32x4 z = (f32x4){0.f, 0.f, 0.f, 0.f};
    #pragma unroll
    for (int qi = 0; qi < 4; qi++) {
      f32x4 s0 = mfma16(ka0, qf[qi], z);
      f32x4 s1 = mfma16(ka1, qf[qi], z);
      float p[8], ls = 0.f;
      #pragma unroll
      for (int j = 0; j < 4; j++) {
        p[j] = __builtin_amdgcn_exp2f(fminf(s0[j], 80.f));
        p[4 + j] = __builtin_amdgcn_exp2f(fminf(s1[j], 80.f));
      }
      #pragma unroll
      for (int j = 0; j < 8; j++) ls += p[j];
      lr[qi] += ls;
      bf16x8 pb;                      // B-operand: k = qd*8+j == key-in-chunk
      #pragma unroll
      for (int j = 0; j < 8; j++) pb[j] = (bf16)p[j];
      acc[qi][0] = mfma16(va0, pb, acc[qi][0]);
      acc[qi][1] = mfma16(va1, pb, acc[qi][1]);
    }
    ka0 = nk0; ka1 = nk1; va0 = nv0; va1 = nv1;
  }
  #pragma unroll
  for (int qi = 0; qi < 4; qi++) {
    float l = lr[qi];
    l += __shfl_xor(l, 16, 64);
    l += __shfl_xor(l, 32, 64);
    const float inv = 1.f / l;
    const int nn = nt * 256 + wv * 64 + qi * 16 + l15;
    float* ob = out + (size_t)(b * 4096 + nn) * 256 + h * 32;
    #pragma unroll
    for (int t = 0; t < 2; t++) {
      *(float4*)(ob + t * 16 + qd * 4) =
          (float4){acc[qi][t][0] * inv, acc[qi][t][1] * inv,
                   acc[qi][t][2] * inv, acc[qi][t][3] * inv};
    }
  }
}

// ---------------------------------------------------------------------------
extern "C" void kernel_launch(void* const* d_in, const int* in_sizes, int n_in,
                              void* d_out, int out_size, void* d_ws, size_t ws_size,
                              hipStream_t stream) {
  const float* x      = (const float*)d_in[0];
  // d_in[1]=h, d_in[2]=w (64, 64) — compile-time constants here
  const float* Wq     = (const float*)d_in[3];
  const float* bq     = (const float*)d_in[4];
  const float* Wkv    = (const float*)d_in[5];
  const float* bkv    = (const float*)d_in[6];
  const float* sr_w1  = (const float*)d_in[7];
  const float* bn1_g  = (const float*)d_in[8];
  const float* bn1_b  = (const float*)d_in[9];
  const float* bn1_m  = (const float*)d_in[10];
  const float* bn1_v  = (const float*)d_in[11];
  const float* sw2    = (const float*)d_in[12];
  const float* bn2_g  = (const float*)d_in[13];
  const float* bn2_b  = (const float*)d_in[14];
  const float* bn2_m  = (const float*)d_in[15];
  const float* bn2_v  = (const float*)d_in[16];
  const float* lw     = (const float*)d_in[17];
  const float* lb     = (const float*)d_in[18];

  const int B = in_sizes[0] / (4096 * 256);   // = 8

  // workspace (~3.4 MB): Wqb 128K | Wkvb 256K | kv1 / K / V 1 MB each
  bf16* Wqb  = (bf16*)d_ws;                        // 65536 elems
  bf16* Wkvb = Wqb + 65536;                        // 131072 elems
  bf16* kv1  = Wkvb + 131072;                      // (B,256,256)
  bf16* k_a  = kv1 + (size_t)B * 256 * 256;        // (bh,256,32)
  bf16* v_b  = k_a + (size_t)B * 8 * 256 * 32;     // (bh,32,256)

  const int nsr = 256 * B;                         // sr blocks (B=8 -> &7 ok)

  k_pre<<<dim3(nsr + 96), 256, 0, stream>>>(
      x, sr_w1, bn1_g, bn1_b, bn1_m, bn1_v, sw2, bn2_g, bn2_b, bn2_m, bn2_v,
      Wq, Wkv, Wqb, Wkvb, kv1, nsr);
  k_localkv<<<dim3(32, B), 256, 0, stream>>>(kv1, lw, lb, Wkvb, bkv, k_a, v_b);
  k_qattn<<<dim3(16, 8, B), 256, 0, stream>>>(x, Wqb, bq, k_a, v_b,
                                              (float*)d_out);
}

// Round 10
// 204.051 us; speedup vs baseline: 1.1371x; 1.1371x over previous
//
#include <hip/hip_runtime.h>
#include <math.h>

typedef __bf16 bf16;
typedef bf16 bf16x4 __attribute__((ext_vector_type(4)));
typedef bf16 bf16x8 __attribute__((ext_vector_type(8)));
typedef float f32x4 __attribute__((ext_vector_type(4)));

static_assert(sizeof(bf16x8) == 16, "bf16x8 must be 16B");

// q pre-scale: (1/sqrt(hd=32)) * log2(e)  -> softmax via exp2
#define QSCALE (0.17677669529663687f * 1.4426950408889634f)

__device__ __forceinline__ f32x4 mfma16(bf16x8 a, bf16x8 b, f32x4 c) {
  return __builtin_amdgcn_mfma_f32_16x16x32_bf16(a, b, c, 0, 0, 0);
}

// ---------------------------------------------------------------------------
// 1) FUSED sr conv + weight prep (no w7t table needed: per-team CONTIGUOUS
//    tap ranges make each channel's 13 weights mergeable into dwordx4 loads).
//    blocks [0, nsr): dwconv7x7 s4 p3 + BN1 + GELU + scale + BN2 -> kv1 bf16
//    blocks [nsr, nsr+96): Wq->bf16 (32), Wkv->bf16 (64)
//    r5/r9 lesson: issue ALL loads into register arrays before any use;
//    verify VGPR_Count >~100 in the CSV, else the loads serialized.
// ---------------------------------------------------------------------------
__global__ __launch_bounds__(256) void k_pre(
    const float* __restrict__ x, const float* __restrict__ w7,
    const float* __restrict__ g1, const float* __restrict__ b1,
    const float* __restrict__ m1, const float* __restrict__ v1,
    const float* __restrict__ sw2,
    const float* __restrict__ g2, const float* __restrict__ b2,
    const float* __restrict__ m2, const float* __restrict__ v2,
    const float* __restrict__ Wq, const float* __restrict__ Wkv,
    bf16* __restrict__ Wqb, bf16* __restrict__ Wkvb,
    bf16* __restrict__ kv1, int nsr) {
  __shared__ float part[4][256];
  const int tid = threadIdx.x;
  const int blk = blockIdx.x;

  if (blk >= nsr) {                              // ---- weight conversion ----
    const int wb = blk - nsr;                    // 32 Wq blocks + 64 Wkv blocks
    const float* src;
    bf16* dst;
    if (wb < 32) {
      const int idx = wb * 256 + tid;            // Wq: 65536/8 = 8192 pieces
      src = Wq + (size_t)idx * 8;
      dst = Wqb + (size_t)idx * 8;
    } else {
      const int idx = (wb - 32) * 256 + tid;     // Wkv: 131072/8 = 16384
      src = Wkv + (size_t)idx * 8;
      dst = Wkvb + (size_t)idx * 8;
    }
    const float4 a = ((const float4*)src)[0];
    const float4 b = ((const float4*)src)[1];
    bf16x8 r;
    r[0] = (bf16)a.x; r[1] = (bf16)a.y; r[2] = (bf16)a.z; r[3] = (bf16)a.w;
    r[4] = (bf16)b.x; r[5] = (bf16)b.y; r[6] = (bf16)b.z; r[7] = (bf16)b.w;
    *(bf16x8*)dst = r;
    return;
  }
  // ---- sr conv: 64 ch-groups x 4 tap-teams (team == wave) ----
  // team tap ranges (contiguous!): t0: 0..12 (13), t1: 13..24, t2: 25..36,
  // t3: 37..48 (12 each).
  const int team = tid >> 6, g = tid & 63;
  const int c0 = g * 4;
  const int base = (team == 0) ? 0 : (1 + team * 12);   // 0,13,25,37
  const int cnt  = (team == 0) ? 13 : 12;               // wave-uniform
  const int b = blk & 7, m = blk >> 3;
  const int oy = m >> 4, ox = m & 15;

  // weights: 13 contiguous floats per channel -> merged vector loads
  float w[4][13];
  #pragma unroll
  for (int i = 0; i < 4; i++) {
    const float* wp = w7 + (size_t)(c0 + i) * 49 + base;
    #pragma unroll
    for (int j = 0; j < 12; j++) w[i][j] = wp[j];
    w[i][12] = wp[cnt == 13 ? 12 : 11];     // avoid OOB at c=255,tap=49
  }
  float4 xv[13];
  float msk[13];
  #pragma unroll
  for (int j = 0; j < 13; j++) {            // issue ALL x loads first
    const int tap = base + (j < cnt ? j : 0);
    const int ky = tap / 7, kx = tap - ky * 7;
    const int iy = oy * 4 - 3 + ky, ix = ox * 4 - 3 + kx;
    msk[j] = (j < cnt && iy >= 0 && iy < 64 && ix >= 0 && ix < 64) ? 1.f : 0.f;
    const int iyc = iy < 0 ? 0 : (iy > 63 ? 63 : iy);
    const int ixc = ix < 0 ? 0 : (ix > 63 ? 63 : ix);
    xv[j] = *(const float4*)(x + ((size_t)b * 4096 + iyc * 64 + ixc) * 256 + c0);
  }
  float a0 = 0.f, a1 = 0.f, a2 = 0.f, a3 = 0.f;
  #pragma unroll
  for (int j = 0; j < 13; j++) {
    a0 += xv[j].x * w[0][j] * msk[j];
    a1 += xv[j].y * w[1][j] * msk[j];
    a2 += xv[j].z * w[2][j] * msk[j];
    a3 += xv[j].w * w[3][j] * msk[j];
  }
  *(f32x4*)&part[team][c0] = (f32x4){a0, a1, a2, a3};
  __syncthreads();
  const int c = tid;
  float y = part[0][c] + part[1][c] + part[2][c] + part[3][c];
  float s = g1[c] / sqrtf(v1[c] + 1e-5f);
  y = y * s + (b1[c] - m1[c] * s);
  y = 0.5f * y * (1.f + erff(y * 0.70710678118654752f));   // exact GELU
  y *= sw2[c];
  s = g2[c] / sqrtf(v2[c] + 1e-5f);
  y = y * s + (b2[c] - m2[c] * s);
  kv1[((size_t)b * 256 + m) * 256 + c] = (bf16)y;
}

// ---------------------------------------------------------------------------
// 2a) local dw3x3(+bias+residual) + KV projection body (r7/r8 proven).
// ---------------------------------------------------------------------------
__device__ __forceinline__ void localkv_body(
    char* smem, int mt, int b,
    const bf16* __restrict__ kv1, const float* __restrict__ w3,
    const float* __restrict__ lb, const bf16* __restrict__ Wkvb,
    const float* __restrict__ bkv, bf16* __restrict__ k_a,
    bf16* __restrict__ v_b) {
  bf16 (*halo)[10][256] = (bf16(*)[10][256])smem;            // 15360 B
  float (*rows)[256] = (float(*)[256])(smem + 15360);        // 8192 B
  const int c = threadIdx.x;
  const int oy = mt >> 1, o0 = (mt & 1) * 8;

  #pragma unroll
  for (int p = 0; p < 30; p++) {
    const int dy = p / 10, xi = p - dy * 10;
    const int iy = oy - 1 + dy, ix = o0 - 1 + xi;
    const bool ok = (iy >= 0 && iy < 16 && ix >= 0 && ix < 16);
    const int iyc = ok ? iy : 0, ixc = ok ? ix : 0;
    const bf16 v = kv1[((size_t)b * 256 + iyc * 16 + ixc) * 256 + c];
    halo[dy][xi][c] = ok ? v : (bf16)0.f;
  }
  float w3f[9];
  #pragma unroll
  for (int t = 0; t < 9; t++) w3f[t] = w3[c * 9 + t];
  const float lbf = lb[c];
  __syncthreads();

  #pragma unroll
  for (int r = 0; r < 8; r++) {
    float acc = lbf + (float)halo[1][r + 1][c];   // bias + residual center
    #pragma unroll
    for (int ky = 0; ky < 3; ky++)
      #pragma unroll
      for (int kx = 0; kx < 3; kx++)
        acc += (float)halo[ky][r + kx][c] * w3f[ky * 3 + kx];
    rows[r][c] = acc;
  }
  __syncthreads();

  const int tid = c;
  float acck[8] = {0}, accv[8] = {0};
  for (int oc = 0; oc < 32; oc++) {
    const bf16x8 w0 = *(const bf16x8*)(Wkvb + (size_t)tid * 256 + oc * 8);
    const bf16x8 w1 = *(const bf16x8*)(Wkvb + ((size_t)tid + 256) * 256 + oc * 8);
    float wf0[8], wf1[8];
    #pragma unroll
    for (int j = 0; j < 8; j++) { wf0[j] = (float)w0[j]; wf1[j] = (float)w1[j]; }
    #pragma unroll
    for (int r = 0; r < 8; r++) {
      const float4* rp = (const float4*)&rows[r][oc * 8];
      const float4 ra = rp[0], rb = rp[1];
      const float rv[8] = {ra.x, ra.y, ra.z, ra.w, rb.x, rb.y, rb.z, rb.w};
      #pragma unroll
      for (int j = 0; j < 8; j++) {
        acck[r] += wf0[j] * rv[j];
        accv[r] += wf1[j] * rv[j];
      }
    }
  }
  const float bk = bkv[tid], bv = bkv[tid + 256];
  const int h = tid >> 5, d = tid & 31;
  #pragma unroll
  for (int r = 0; r < 8; r++) {
    const int m = (oy * 16 + o0) + r;
    k_a[(((size_t)b * 8 + h) * 256 + m) * 32 + d] = (bf16)(acck[r] + bk);
    v_b[(((size_t)b * 8 + h) * 32 + d) * 256 + m] = (bf16)(accv[r] + bv);
  }
}

// ---------------------------------------------------------------------------
// 2b) Q projection body (r8 proven): block = 32 rows, wave = 32 rows x 64
//     cols (each B-frag feeds 2 MFMAs). q bf16 -> q_ws (bh, n, 32).
// ---------------------------------------------------------------------------
__device__ __forceinline__ void qproj_body(
    char* smem, int qblk,
    const float* __restrict__ x, const bf16* __restrict__ Wqb,
    const float* __restrict__ bq, bf16* __restrict__ q_ws) {
  bf16* xs = (bf16*)smem;                      // 32 rows x 264 elems (16.9 KB)
  const int tid = threadIdx.x, wv = tid >> 6, lane = tid & 63;
  const int qd = lane >> 4, l15 = lane & 15;
  const size_t rowbase = (size_t)qblk * 32;

  #pragma unroll
  for (int it = 0; it < 4; it++) {             // stage 32 rows x 256 ch fp32
    const int idx = it * 256 + tid;
    const int lr = idx >> 5, pos = idx & 31;   // pos = 8-ch piece within row
    const float* src = x + (rowbase + lr) * 256 + pos * 8;
    const float4 a = ((const float4*)src)[0];
    const float4 b = ((const float4*)src)[1];
    bf16x8 r;
    r[0] = (bf16)a.x; r[1] = (bf16)a.y; r[2] = (bf16)a.z; r[3] = (bf16)a.w;
    r[4] = (bf16)b.x; r[5] = (bf16)b.y; r[6] = (bf16)b.z; r[7] = (bf16)b.w;
    *(bf16x8*)(xs + lr * 264 + pos * 8) = r;
  }
  __syncthreads();

  f32x4 acc0[4], acc1[4];
  #pragma unroll
  for (int dt = 0; dt < 4; dt++) {
    acc0[dt] = (f32x4){0.f, 0.f, 0.f, 0.f};
    acc1[dt] = (f32x4){0.f, 0.f, 0.f, 0.f};
  }
  #pragma unroll 2
  for (int kc = 0; kc < 8; kc++) {
    const bf16x8 a0 = *(const bf16x8*)(xs + l15 * 264 + kc * 32 + qd * 8);
    const bf16x8 a1 = *(const bf16x8*)(xs + (16 + l15) * 264 + kc * 32 + qd * 8);
    #pragma unroll
    for (int dt = 0; dt < 4; dt++) {
      const int d = wv * 64 + dt * 16 + l15;
      const bf16x8 bb = *(const bf16x8*)(Wqb + (size_t)d * 256 + kc * 32 + qd * 8);
      acc0[dt] = mfma16(a0, bb, acc0[dt]);
      acc1[dt] = mfma16(a1, bb, acc1[dt]);
    }
  }
  #pragma unroll
  for (int dt = 0; dt < 4; dt++) {
    const int d = wv * 64 + dt * 16 + l15;        // D col = l15 -> channel d
    const float bias = bq[d];
    const int h = d >> 5, dl = d & 31;
    #pragma unroll
    for (int r = 0; r < 4; r++) {
      const size_t row0 = rowbase + qd * 4 + r;          // global b*4096+nn
      const size_t row1 = rowbase + 16 + qd * 4 + r;
      q_ws[(((row0 >> 12) * 8 + h) * 4096 + (row0 & 4095)) * 32 + dl] =
          (bf16)((acc0[dt][r] + bias) * QSCALE);
      q_ws[(((row1 >> 12) * 8 + h) * 4096 + (row1 & 4095)) * 32 + dl] =
          (bf16)((acc1[dt][r] + bias) * QSCALE);
    }
  }
}

// ---------------------------------------------------------------------------
// 2) MERGED mid kernel: blocks [0,256) localkv, [256, 256+B*128) qproj.
//    The two bodies are mutually independent (both consume only k_pre
//    outputs), so block-range splitting is race-free.
// ---------------------------------------------------------------------------
__global__ __launch_bounds__(256) void k_mid(
    const bf16* __restrict__ kv1, const float* __restrict__ w3,
    const float* __restrict__ lb, const bf16* __restrict__ Wkvb,
    const float* __restrict__ bkv, bf16* __restrict__ k_a,
    bf16* __restrict__ v_b,
    const float* __restrict__ x, const bf16* __restrict__ Wqb,
    const float* __restrict__ bq, bf16* __restrict__ q_ws) {
  __shared__ char smem[23552];    // max(localkv 23552, qproj 16896)
  const int blk = blockIdx.x;
  if (blk < 256)
    localkv_body(smem, blk & 31, blk >> 5, kv1, w3, lb, Wkvb, bkv, k_a, v_b);
  else
    qproj_body(smem, blk - 256, x, Wqb, bq, q_ws);
}

// ---------------------------------------------------------------------------
// 3) attention (r8 proven): no-max softmax (shift-invariant; clamp is a pure
//    overflow guard). Per (b,h): S^T = K.Q^T, p = exp2(s), O^T = V^T.P^T.
//    grid (16, 8, B), 256 thr; wave = 64 queries (4 tiles of 16).
//    K rows permuted at load so P lands directly in B-operand layout.
// ---------------------------------------------------------------------------
__global__ __launch_bounds__(256) void k_attn(
    const bf16* __restrict__ q_ws, const bf16* __restrict__ k_a,
    const bf16* __restrict__ v_b, float* __restrict__ out) {
  const int tid = threadIdx.x;
  const int wv = tid >> 6, lane = tid & 63;
  const int qd = lane >> 4, l15 = lane & 15;
  const int b = blockIdx.z, h = blockIdx.y;
  const int bh = b * 8 + h;
  const int n_base = blockIdx.x * 256 + wv * 64;

  const bf16* qb = q_ws + ((size_t)bh * 4096 + n_base) * 32;
  bf16x8 qf[4];   // B-operand: lane holds Q^T[d=qd*8+j][query=l15]
  #pragma unroll
  for (int qi = 0; qi < 4; qi++)
    qf[qi] = *(const bf16x8*)(qb + (size_t)(qi * 16 + l15) * 32 + qd * 8);

  const bf16* kb = k_a + (size_t)bh * 256 * 32;
  const bf16* vb = v_b + (size_t)bh * 32 * 256;

  f32x4 acc[4][2];
  float lr[4] = {0.f, 0.f, 0.f, 0.f};
  #pragma unroll
  for (int qi = 0; qi < 4; qi++) {
    acc[qi][0] = (f32x4){0.f, 0.f, 0.f, 0.f};
    acc[qi][1] = (f32x4){0.f, 0.f, 0.f, 0.f};
  }
  // permuted key row: A-tile t row l15 holds key 8*(l15>>2) + 4*t + (l15&3)
  const int kperm = 8 * (l15 >> 2) + (l15 & 3);

  bf16x8 ka0 = *(const bf16x8*)(kb + (size_t)kperm * 32 + qd * 8);
  bf16x8 ka1 = *(const bf16x8*)(kb + (size_t)(kperm + 4) * 32 + qd * 8);
  bf16x8 va0 = *(const bf16x8*)(vb + (size_t)l15 * 256 + qd * 8);
  bf16x8 va1 = *(const bf16x8*)(vb + (size_t)(16 + l15) * 256 + qd * 8);

  for (int ch = 0; ch < 8; ch++) {               // 8 chunks x 32 keys
    const int cn = (ch < 7 ? ch + 1 : 7) * 32;   // prefetch next (clamped)
    const bf16x8 nk0 = *(const bf16x8*)(kb + (size_t)(cn + kperm) * 32 + qd * 8);
    const bf16x8 nk1 = *(const bf16x8*)(kb + (size_t)(cn + kperm + 4) * 32 + qd * 8);
    const bf16x8 nv0 = *(const bf16x8*)(vb + (size_t)l15 * 256 + cn + qd * 8);
    const bf16x8 nv1 = *(const bf16x8*)(vb + (size_t)(16 + l15) * 256 + cn + qd * 8);
    const f32x4 z = (f32x4){0.f, 0.f, 0.f, 0.f};
    #pragma unroll
    for (int qi = 0; qi < 4; qi++) {
      f32x4 s0 = mfma16(ka0, qf[qi], z);
      f32x4 s1 = mfma16(ka1, qf[qi], z);
      float p[8], ls = 0.f;
      #pragma unroll
      for (int j = 0; j < 4; j++) {
        p[j] = __builtin_amdgcn_exp2f(fminf(s0[j], 80.f));
        p[4 + j] = __builtin_amdgcn_exp2f(fminf(s1[j], 80.f));
      }
      #pragma unroll
      for (int j = 0; j < 8; j++) ls += p[j];
      lr[qi] += ls;
      bf16x8 pb;                      // B-operand: k = qd*8+j == key-in-chunk
      #pragma unroll
      for (int j = 0; j < 8; j++) pb[j] = (bf16)p[j];
      acc[qi][0] = mfma16(va0, pb, acc[qi][0]);
      acc[qi][1] = mfma16(va1, pb, acc[qi][1]);
    }
    ka0 = nk0; ka1 = nk1; va0 = nv0; va1 = nv1;
  }
  #pragma unroll
  for (int qi = 0; qi < 4; qi++) {
    float l = lr[qi];
    l += __shfl_xor(l, 16, 64);
    l += __shfl_xor(l, 32, 64);
    const float inv = 1.f / l;
    const int nn = n_base + qi * 16 + l15;
    float* ob = out + (size_t)(b * 4096 + nn) * 256 + h * 32;
    #pragma unroll
    for (int t = 0; t < 2; t++) {
      *(float4*)(ob + t * 16 + qd * 4) =
          (float4){acc[qi][t][0] * inv, acc[qi][t][1] * inv,
                   acc[qi][t][2] * inv, acc[qi][t][3] * inv};
    }
  }
}

// ---------------------------------------------------------------------------
extern "C" void kernel_launch(void* const* d_in, const int* in_sizes, int n_in,
                              void* d_out, int out_size, void* d_ws, size_t ws_size,
                              hipStream_t stream) {
  const float* x      = (const float*)d_in[0];
  // d_in[1]=h, d_in[2]=w (64, 64) — compile-time constants here
  const float* Wq     = (const float*)d_in[3];
  const float* bq     = (const float*)d_in[4];
  const float* Wkv    = (const float*)d_in[5];
  const float* bkv    = (const float*)d_in[6];
  const float* sr_w1  = (const float*)d_in[7];
  const float* bn1_g  = (const float*)d_in[8];
  const float* bn1_b  = (const float*)d_in[9];
  const float* bn1_m  = (const float*)d_in[10];
  const float* bn1_v  = (const float*)d_in[11];
  const float* sw2    = (const float*)d_in[12];
  const float* bn2_g  = (const float*)d_in[13];
  const float* bn2_b  = (const float*)d_in[14];
  const float* bn2_m  = (const float*)d_in[15];
  const float* bn2_v  = (const float*)d_in[16];
  const float* lw     = (const float*)d_in[17];
  const float* lb     = (const float*)d_in[18];

  const int B = in_sizes[0] / (4096 * 256);   // = 8

  // workspace (~20 MB of the 256 MB d_ws):
  bf16* Wqb  = (bf16*)d_ws;                        // 65536 elems
  bf16* Wkvb = Wqb + 65536;                        // 131072 elems
  bf16* kv1  = Wkvb + 131072;                      // (B,256,256)
  bf16* k_a  = kv1 + (size_t)B * 256 * 256;        // (bh,256,32)
  bf16* v_b  = k_a + (size_t)B * 8 * 256 * 32;     // (bh,32,256)
  bf16* q_ws = v_b + (size_t)B * 8 * 32 * 256;     // (bh,4096,32) 16.8 MB

  const int nsr = 256 * B;                         // sr blocks (B=8 -> &7 ok)

  k_pre<<<dim3(nsr + 96), 256, 0, stream>>>(
      x, sr_w1, bn1_g, bn1_b, bn1_m, bn1_v, sw2, bn2_g, bn2_b, bn2_m, bn2_v,
      Wq, Wkv, Wqb, Wkvb, kv1, nsr);
  k_mid<<<dim3(256 + B * 128), 256, 0, stream>>>(
      kv1, lw, lb, Wkvb, bkv, k_a, v_b, x, Wqb, bq, q_ws);
  k_attn<<<dim3(16, 8, B), 256, 0, stream>>>(q_ws, k_a, v_b, (float*)d_out);
}